// Round 1
// baseline (324.921 us; speedup 1.0000x reference)
//
#include <hip/hip_runtime.h>
#include <math.h>

#define HDIM 512
#define EPS_DIAG 0.1f

__device__ __forceinline__ float fast_tanh(float x) {
    // tanh(x) = 1 - 2/(1 + exp(2x)); stable at both tails:
    //   x >> 0: exp->inf, rcp->0, result 1
    //   x << 0: exp->0,  rcp->1, result -1
    float e = __expf(2.0f * x);
    return fmaf(-2.0f, __builtin_amdgcn_rcpf(1.0f + e), 1.0f);
}

__global__ __launch_bounds__(256) void dyn_kernel(
    const float* __restrict__ q, const float* __restrict__ q_dot,
    const float* __restrict__ s, const float* __restrict__ s_Ddot,
    const float* __restrict__ tau,
    const float* __restrict__ fv, const float* __restrict__ fc,
    const float* __restrict__ W1m, const float* __restrict__ b1m,
    const float* __restrict__ W2m, const float* __restrict__ b2m,
    const float* __restrict__ W1g, const float* __restrict__ b1g,
    const float* __restrict__ W2g, const float* __restrict__ b2g,
    const float* __restrict__ W1k, const float* __restrict__ b1k,
    const float* __restrict__ W2k, const float* __restrict__ b2k,
    float* __restrict__ out, int n)
{
    const int i = blockIdx.x * blockDim.x + threadIdx.x;
    if (i >= n) return;

    // Per-sample inputs (coalesced-ish: 12B/thread contiguous)
    const float q0 = q[3*i+0], q1 = q[3*i+1], q2 = q[3*i+2];
    const float s0 = s[3*i+0], s1 = s[3*i+1], s2 = s[3*i+2];
    const float d0 = s_Ddot[3*i+0], d1 = s_Ddot[3*i+1], d2 = s_Ddot[3*i+2];

    // Accumulators initialized with second-layer biases (uniform scalar loads)
    float aM0 = b2m[0], aM1 = b2m[1], aM2 = b2m[2],
          aM3 = b2m[3], aM4 = b2m[4], aM5 = b2m[5],
          aM6 = b2m[6], aM7 = b2m[7], aM8 = b2m[8];
    float aG0 = b2g[0], aG1 = b2g[1], aG2 = b2g[2];
    float aK0 = b2k[0], aK1 = b2k[1], aK2 = b2k[2];

    #pragma unroll 4
    for (int h = 0; h < HDIM; ++h) {
        // Mass net pre-activation: q . W1m[:,h] + b1m[h]   (W1m is [3,H] row-major)
        float pm = fmaf(q2, W1m[2*HDIM + h],
                   fmaf(q1, W1m[1*HDIM + h],
                   fmaf(q0, W1m[0*HDIM + h], b1m[h])));
        // Gravity net
        float pg = fmaf(q2, W1g[2*HDIM + h],
                   fmaf(q1, W1g[1*HDIM + h],
                   fmaf(q0, W1g[0*HDIM + h], b1g[h])));
        // KAB net on concat(q, s, s_Ddot)  (W1k is [9,H] row-major)
        float pk = b1k[h];
        pk = fmaf(q0, W1k[0*HDIM + h], pk);
        pk = fmaf(q1, W1k[1*HDIM + h], pk);
        pk = fmaf(q2, W1k[2*HDIM + h], pk);
        pk = fmaf(s0, W1k[3*HDIM + h], pk);
        pk = fmaf(s1, W1k[4*HDIM + h], pk);
        pk = fmaf(s2, W1k[5*HDIM + h], pk);
        pk = fmaf(d0, W1k[6*HDIM + h], pk);
        pk = fmaf(d1, W1k[7*HDIM + h], pk);
        pk = fmaf(d2, W1k[8*HDIM + h], pk);

        const float hm = fast_tanh(pm);
        const float hg = fast_tanh(pg);
        const float hk = fast_tanh(pk);

        // Second layers: W2m [H,9], W2g [H,3], W2k [H,3] row-major (contiguous per h)
        const float* w2m = W2m + h*9;
        aM0 = fmaf(hm, w2m[0], aM0); aM1 = fmaf(hm, w2m[1], aM1); aM2 = fmaf(hm, w2m[2], aM2);
        aM3 = fmaf(hm, w2m[3], aM3); aM4 = fmaf(hm, w2m[4], aM4); aM5 = fmaf(hm, w2m[5], aM5);
        aM6 = fmaf(hm, w2m[6], aM6); aM7 = fmaf(hm, w2m[7], aM7); aM8 = fmaf(hm, w2m[8], aM8);
        const float* w2g = W2g + h*3;
        aG0 = fmaf(hg, w2g[0], aG0); aG1 = fmaf(hg, w2g[1], aG1); aG2 = fmaf(hg, w2g[2], aG2);
        const float* w2k = W2k + h*3;
        aK0 = fmaf(hk, w2k[0], aK0); aK1 = fmaf(hk, w2k[1], aK1); aK2 = fmaf(hk, w2k[2], aK2);
    }

    // M = Mraw @ Mraw^T + eps*I  (Mraw row-major: rows {aM0..2},{aM3..5},{aM6..8})
    const float m00 = aM0*aM0 + aM1*aM1 + aM2*aM2 + EPS_DIAG;
    const float m01 = aM0*aM3 + aM1*aM4 + aM2*aM5;
    const float m02 = aM0*aM6 + aM1*aM7 + aM2*aM8;
    const float m11 = aM3*aM3 + aM4*aM4 + aM5*aM5 + EPS_DIAG;
    const float m12 = aM3*aM6 + aM4*aM7 + aM5*aM8;
    const float m22 = aM6*aM6 + aM7*aM7 + aM8*aM8 + EPS_DIAG;

    // rhs = -G + KAB - fv*q_dot - fc*sign(q_dot) + tau
    const float qd0 = q_dot[3*i+0], qd1 = q_dot[3*i+1], qd2 = q_dot[3*i+2];
    const float t0 = tau[3*i+0], t1 = tau[3*i+1], t2 = tau[3*i+2];
    const float fv0 = fv[0], fv1 = fv[1], fv2 = fv[2];
    const float fc0 = fc[0], fc1 = fc[1], fc2 = fc[2];
    const float sg0 = (qd0 > 0.f) ? 1.f : ((qd0 < 0.f) ? -1.f : 0.f);
    const float sg1 = (qd1 > 0.f) ? 1.f : ((qd1 < 0.f) ? -1.f : 0.f);
    const float sg2 = (qd2 > 0.f) ? 1.f : ((qd2 < 0.f) ? -1.f : 0.f);
    const float r0 = -aG0 + aK0 - fv0*qd0 - fc0*sg0 + t0;
    const float r1 = -aG1 + aK1 - fv1*qd1 - fc1*sg1 + t1;
    const float r2 = -aG2 + aK2 - fv2*qd2 - fc2*sg2 + t2;

    // Symmetric 3x3 inverse via adjugate (M is SPD, det >= ~1e-3)
    const float c00 = m11*m22 - m12*m12;
    const float c01 = m02*m12 - m01*m22;
    const float c02 = m01*m12 - m02*m11;
    const float det = m00*c00 + m01*c01 + m02*c02;
    const float idet = 1.0f / det;  // once per thread; accurate div is fine
    const float i00 = c00*idet, i01 = c01*idet, i02 = c02*idet;
    const float i11 = (m00*m22 - m02*m02)*idet;
    const float i12 = (m01*m02 - m00*m12)*idet;
    const float i22 = (m00*m11 - m01*m01)*idet;

    out[3*i+0] = i00*r0 + i01*r1 + i02*r2;
    out[3*i+1] = i01*r0 + i11*r1 + i12*r2;
    out[3*i+2] = i02*r0 + i12*r1 + i22*r2;
}

extern "C" void kernel_launch(void* const* d_in, const int* in_sizes, int n_in,
                              void* d_out, int out_size, void* d_ws, size_t ws_size,
                              hipStream_t stream) {
    const float* q      = (const float*)d_in[0];
    const float* q_dot  = (const float*)d_in[1];
    const float* s      = (const float*)d_in[2];
    const float* s_Ddot = (const float*)d_in[3];
    const float* tau    = (const float*)d_in[4];
    const float* fv     = (const float*)d_in[5];
    const float* fc     = (const float*)d_in[6];
    const float* W1m    = (const float*)d_in[7];
    const float* b1m    = (const float*)d_in[8];
    const float* W2m    = (const float*)d_in[9];
    const float* b2m    = (const float*)d_in[10];
    const float* W1g    = (const float*)d_in[11];
    const float* b1g    = (const float*)d_in[12];
    const float* W2g    = (const float*)d_in[13];
    const float* b2g    = (const float*)d_in[14];
    const float* W1k    = (const float*)d_in[15];
    const float* b1k    = (const float*)d_in[16];
    const float* W2k    = (const float*)d_in[17];
    const float* b2k    = (const float*)d_in[18];
    float* out = (float*)d_out;

    const int n = in_sizes[0] / 3;  // B
    const int block = 256;
    const int grid = (n + block - 1) / block;
    dyn_kernel<<<grid, block, 0, stream>>>(q, q_dot, s, s_Ddot, tau, fv, fc,
                                           W1m, b1m, W2m, b2m,
                                           W1g, b1g, W2g, b2g,
                                           W1k, b1k, W2k, b2k,
                                           out, n);
}